// Round 1
// baseline (453.970 us; speedup 1.0000x reference)
//
#include <hip/hip_runtime.h>

constexpr int NB    = 8;     // batches
constexpr int NN    = 256;   // sequence length
constexpr int F0    = 512;
constexpr int F1    = 256;
constexpr int F2    = 128;
constexpr int ROWS  = NB * NN;   // 2048
constexpr int KMAX  = 30;

// ---------------- fp32 GEMM: C = act(A @ B + bias), 64x32 tile, BK=16 ----------
__global__ __launch_bounds__(256) void gemm_bias_act(
    const float* __restrict__ A, const float* __restrict__ B,
    const float* __restrict__ bias, float* __restrict__ C,
    int M, int Ncols, int K, int relu)
{
  __shared__ float As[16][64];   // [k][m]
  __shared__ float Bs[16][32];   // [k][n]
  const int tid = threadIdx.x;
  const int tx = tid & 15;       // col group  (2 cols)
  const int ty = tid >> 4;       // row group  (4 rows)
  const int rowBase = blockIdx.y * 64;
  const int colBase = blockIdx.x * 32;
  float acc[4][2] = {};
  for (int k0 = 0; k0 < K; k0 += 16) {
    {
      const int r  = tid >> 2;
      const int kq = (tid & 3) << 2;
      const float4 av = *(const float4*)(A + (size_t)(rowBase + r) * K + (k0 + kq));
      As[kq+0][r] = av.x; As[kq+1][r] = av.y; As[kq+2][r] = av.z; As[kq+3][r] = av.w;
      const int kr = tid >> 4;
      const int c2 = (tid & 15) << 1;
      const float2 bv = *(const float2*)(B + (size_t)(k0 + kr) * Ncols + (colBase + c2));
      Bs[kr][c2+0] = bv.x; Bs[kr][c2+1] = bv.y;
    }
    __syncthreads();
    #pragma unroll
    for (int kk = 0; kk < 16; kk++) {
      const float4 a = *(const float4*)&As[kk][ty*4];
      const float b0v = Bs[kk][tx*2+0];
      const float b1v = Bs[kk][tx*2+1];
      acc[0][0] += a.x*b0v; acc[0][1] += a.x*b1v;
      acc[1][0] += a.y*b0v; acc[1][1] += a.y*b1v;
      acc[2][0] += a.z*b0v; acc[2][1] += a.z*b1v;
      acc[3][0] += a.w*b0v; acc[3][1] += a.w*b1v;
    }
    __syncthreads();
  }
  #pragma unroll
  for (int i = 0; i < 4; i++) {
    const int rr = rowBase + ty*4 + i;
    #pragma unroll
    for (int j = 0; j < 2; j++) {
      const int cc = colBase + tx*2 + j;
      float v = acc[i][j] + bias[cc];
      if (relu) v = fmaxf(v, 0.0f);
      C[(size_t)rr * Ncols + cc] = v;
    }
  }
}

// ---------------- row norms: norms[r] = ||z_r||^2, one wave per row ------------
__global__ __launch_bounds__(256) void row_norms(
    const float* __restrict__ z, float* __restrict__ norms)
{
  const int wave = (blockIdx.x * blockDim.x + threadIdx.x) >> 6;
  const int lane = threadIdx.x & 63;
  if (wave >= ROWS) return;
  const float* p = z + (size_t)wave * F2;
  float a = p[lane], b = p[lane + 64];
  float v = a*a + b*b;
  #pragma unroll
  for (int d = 32; d; d >>= 1) v += __shfl_xor(v, d);
  if (lane == 0) norms[wave] = v;
}

// ---------------- D[b,n,m] = 0.5*(1 - (z_n.z_m)/sqrt(max(|z_n|^2|z_m|^2,1e-8)))
__global__ __launch_bounds__(256) void corr_dist(
    const float* __restrict__ z, const float* __restrict__ norms,
    float* __restrict__ D)
{
  const int b = blockIdx.z;
  const float* zb = z + (size_t)b * NN * F2;
  __shared__ float As[16][64];  // [k][row]
  __shared__ float Bs[16][64];  // [k][col]
  const int tid = threadIdx.x;
  const int tx = tid & 15;
  const int ty = tid >> 4;
  const int rowBase = blockIdx.y * 64;
  const int colBase = blockIdx.x * 64;
  float acc[4][4] = {};
  for (int k0 = 0; k0 < F2; k0 += 16) {
    {
      const int r  = tid >> 2;
      const int kq = (tid & 3) << 2;
      const float4 av = *(const float4*)(zb + (size_t)(rowBase + r) * F2 + (k0 + kq));
      As[kq+0][r] = av.x; As[kq+1][r] = av.y; As[kq+2][r] = av.z; As[kq+3][r] = av.w;
      const float4 bv = *(const float4*)(zb + (size_t)(colBase + r) * F2 + (k0 + kq));
      Bs[kq+0][r] = bv.x; Bs[kq+1][r] = bv.y; Bs[kq+2][r] = bv.z; Bs[kq+3][r] = bv.w;
    }
    __syncthreads();
    #pragma unroll
    for (int kk = 0; kk < 16; kk++) {
      const float4 a = *(const float4*)&As[kk][ty*4];
      const float4 bq = *(const float4*)&Bs[kk][tx*4];
      const float ar[4] = {a.x, a.y, a.z, a.w};
      const float br[4] = {bq.x, bq.y, bq.z, bq.w};
      #pragma unroll
      for (int i = 0; i < 4; i++)
        #pragma unroll
        for (int j = 0; j < 4; j++)
          acc[i][j] += ar[i] * br[j];
    }
    __syncthreads();
  }
  float* Db = D + (size_t)b * NN * NN;
  #pragma unroll
  for (int i = 0; i < 4; i++) {
    const int rr = rowBase + ty*4 + i;
    const float nr = norms[b*NN + rr];
    #pragma unroll
    for (int j = 0; j < 4; j++) {
      const int cc = colBase + tx*4 + j;
      const float nc = norms[b*NN + cc];
      const float denom = sqrtf(fmaxf(nr * nc, 1e-8f));
      Db[(size_t)rr * NN + cc] = 0.5f * (1.0f - acc[i][j] / denom);
    }
  }
}

// ---------------- fused 2D prefix (fp64) + 29-step softmax DP, 1 block/batch ---
// Ds[n,i] (i>=n) = S[i][i] - 2*S[n-1][i] + S[n-1][n-1]   (S symmetric since D is)
__global__ __launch_bounds__(1024) void scan_dp(
    const float* __restrict__ D, double* __restrict__ S,
    float* __restrict__ out)
{
  const int b = blockIdx.x;
  const float*  Db = D + (size_t)b * NN * NN;
  double*       Sb = S + (size_t)b * NN * NN;
  const int tid  = threadIdx.x;
  const int w    = tid >> 6;     // wave 0..15
  const int lane = tid & 63;

  __shared__ double diagd[NN];
  __shared__ float  cbuf[2][NN + 1];
  __shared__ float  outAcc[NN];

  // Phase 1: row-wise inclusive scans (fp64), wave w handles rows [16w,16w+16)
  for (int t = 0; t < 16; t++) {
    const int r = w * 16 + t;
    const float* drow = Db + (size_t)r * NN;
    double* srow = Sb + (size_t)r * NN;
    double carry = 0.0;
    #pragma unroll
    for (int c = 0; c < 4; c++) {
      double v = (double)drow[c*64 + lane];
      #pragma unroll
      for (int d = 1; d < 64; d <<= 1) {
        double u = __shfl_up(v, d);
        if (lane >= d) v += u;
      }
      v += carry;
      srow[c*64 + lane] = v;
      carry = __shfl(v, 63);
    }
  }
  __syncthreads();

  // Phase 2: column-wise scans, waves 0..3 handle 64-column groups
  if (w < 4) {
    const int c = w * 64 + lane;
    double sum = 0.0;
    for (int r = 0; r < NN; r += 4) {
      double v0 = Sb[(size_t)(r+0)*NN + c];
      double v1 = Sb[(size_t)(r+1)*NN + c];
      double v2 = Sb[(size_t)(r+2)*NN + c];
      double v3 = Sb[(size_t)(r+3)*NN + c];
      v0 += sum; v1 += v0; v2 += v1; v3 += v2;
      Sb[(size_t)(r+0)*NN + c] = v0;
      Sb[(size_t)(r+1)*NN + c] = v1;
      Sb[(size_t)(r+2)*NN + c] = v2;
      Sb[(size_t)(r+3)*NN + c] = v3;
      sum = v3;
    }
  }
  __syncthreads();

  // Phase 3a: diagonal to LDS, zero output accumulator
  if (tid < NN) {
    diagd[tid]  = Sb[(size_t)tid * NN + tid];
    outAcc[tid] = 0.0f;
  }
  if (tid == 0) { cbuf[0][NN] = 0.0f; cbuf[1][NN] = 0.0f; }
  __syncthreads();

  // Phase 3b: initial C_prev[n] = Ds[n, N-1]
  if (tid < NN) {
    const int n = tid;
    double c0 = diagd[NN-1];
    if (n > 0) c0 += -2.0 * Sb[(size_t)(n-1)*NN + (NN-1)] + diagd[n-1];
    cbuf[0][n] = (float)c0;
  }

  // Phase 4: load Ds fragment into registers.
  // Wave w owns rows n = w + 16t; lane owns cols j = 64c + lane.
  float dsr[16][4];
  #pragma unroll
  for (int t = 0; t < 16; t++) {
    const int n = w + 16*t;
    const double snn = (n > 0) ? diagd[n-1] : 0.0;
    const double* srow = Sb + (size_t)(n > 0 ? n-1 : 0) * NN;
    const int cstart = n >> 6;
    #pragma unroll
    for (int c = 0; c < 4; c++) {
      float v = 1e30f;
      if (c >= cstart) {
        const int j = c*64 + lane;
        const double sv = (n > 0) ? srow[j] : 0.0;
        v = (float)(diagd[j] - 2.0*sv + snn);
      }
      dsr[t][c] = v;
    }
  }
  __syncthreads();   // cbuf[0] visible to all waves

  // Phase 5: DP over kk = 1..29
  float acc[4] = {0.f, 0.f, 0.f, 0.f};
  for (int kk = 1; kk < KMAX; kk++) {
    const float* Cp = cbuf[(kk+1) & 1];
    float*       Cn = cbuf[kk & 1];
    const int limit = NN - kk;
    #pragma unroll
    for (int t = 0; t < 16; t++) {
      const int n = w + 16*t;            // wave-uniform
      if (n >= limit) {                  // empty valid set -> C_prev := 0
        if (lane == 0) Cn[n] = 0.0f;
        continue;
      }
      const int cstart = n >> 6;
      float tv[4];
      float m = 1e30f;
      #pragma unroll
      for (int c = 0; c < 4; c++) {
        if (c >= cstart) {               // uniform branch (limit>192 always)
          const int j = c*64 + lane;
          const float csh = Cp[j + 1];   // cbuf[.][256]==0 pad
          float tval = dsr[t][c] + csh;
          const bool valid = (j >= n) && (j < limit);
          tval = valid ? tval : 1e30f;
          tv[c] = tval;
          m = fminf(m, tval);
        } else {
          tv[c] = 1e30f;
        }
      }
      #pragma unroll
      for (int d = 32; d; d >>= 1) m = fminf(m, __shfl_xor(m, d));
      float s = 0.0f;
      float ev[4];
      #pragma unroll
      for (int c = 0; c < 4; c++) {
        if (c >= cstart) {
          ev[c] = __expf(m - tv[c]);     // invalid -> exp(-huge) = 0
          s += ev[c];
        }
      }
      #pragma unroll
      for (int d = 32; d; d >>= 1) s += __shfl_xor(s, d);
      const float inv = 1.0f / s;
      #pragma unroll
      for (int c = 0; c < 4; c++) {
        if (c >= cstart) acc[c] += ev[c] * inv;
      }
      if (lane == 0) Cn[n] = m;          // Cmin (softmax max-trick shares the min)
    }
    __syncthreads();
  }

  // Phase 6: reduce per-wave column accumulators, write output
  #pragma unroll
  for (int c = 0; c < 4; c++)
    atomicAdd(&outAcc[c*64 + lane], acc[c]);
  __syncthreads();
  if (tid < NN) {
    const int j = tid;
    int kmax = NN - 1 - j; if (kmax > KMAX - 1) kmax = KMAX - 1;
    const float cnt = (float)((j + 1) * kmax + (j == NN-1 ? NN : 0));
    const float val = outAcc[j] + (j == NN-1 ? (float)NN : 0.0f);
    out[b*NN + j] = val / cnt;
  }
}

extern "C" void kernel_launch(void* const* d_in, const int* in_sizes, int n_in,
                              void* d_out, int out_size, void* d_ws, size_t ws_size,
                              hipStream_t stream) {
  const float* x  = (const float*)d_in[0];
  const float* W0 = (const float*)d_in[1];
  const float* b0 = (const float*)d_in[2];
  const float* W1 = (const float*)d_in[3];
  const float* b1 = (const float*)d_in[4];
  float* out = (float*)d_out;

  // ws layout (bytes): S (fp64, 4 MiB) | h | z | norms | D   -> ~9.4 MiB total
  char* base = (char*)d_ws;
  double* S     = (double*)base;                              // 8*524288
  float*  h     = (float*)(base + 4194304);                   // 2048x256
  float*  z     = (float*)(base + 4194304 + 2097152);         // 2048x128
  float*  norms = (float*)(base + 4194304 + 2097152 + 1048576);
  float*  D     = (float*)(base + 4194304 + 2097152 + 1048576 + 8192);

  gemm_bias_act<<<dim3(F1/32, ROWS/64), 256, 0, stream>>>(x, W0, b0, h, ROWS, F1, F0, 1);
  gemm_bias_act<<<dim3(F2/32, ROWS/64), 256, 0, stream>>>(h, W1, b1, z, ROWS, F2, F1, 0);
  row_norms<<<dim3(ROWS*64/256), 256, 0, stream>>>(z, norms);
  corr_dist<<<dim3(NN/64, NN/64, NB), 256, 0, stream>>>(z, norms, D);
  scan_dp<<<dim3(NB), 1024, 0, stream>>>(D, S, out);
}